// Round 1
// baseline (2946.646 us; speedup 1.0000x reference)
//
#include <hip/hip_runtime.h>
#include <math.h>

#define Bq 2
#define Lq 2048
#define DIMq 768
#define NHq 12
#define HDq 64

// ---------------------------------------------------------------------------
// GEMM: Y = X @ W^T.  X: [M, K] row-major, W: [N, K] row-major (torch Linear).
// headLayout==1: Y written as [B][NH][L][HD] (split heads).
// headLayout==0: Y written as [M][N] flat.
// Tile: BM=BN=64, BK=16, 256 threads, 4x4 per thread.
// ---------------------------------------------------------------------------
__global__ __launch_bounds__(256)
void gemm_xwt(const float* __restrict__ X, const float* __restrict__ W,
              float* __restrict__ Y, int headLayout)
{
    __shared__ float As[16][65];
    __shared__ float Bs[16][65];
    const int tid = threadIdx.x;
    const int tx = tid & 15, ty = tid >> 4;
    const int m0 = blockIdx.y * 64, n0 = blockIdx.x * 64;

    float acc[4][4];
#pragma unroll
    for (int i = 0; i < 4; ++i)
#pragma unroll
        for (int j = 0; j < 4; ++j) acc[i][j] = 0.f;

    for (int k0 = 0; k0 < DIMq; k0 += 16) {
        __syncthreads();
#pragma unroll
        for (int i = 0; i < 4; ++i) {
            int idx = tid + i * 256;
            int kk = idx & 15, mm = idx >> 4;
            As[kk][mm] = X[(size_t)(m0 + mm) * DIMq + k0 + kk];
            Bs[kk][mm] = W[(size_t)(n0 + mm) * DIMq + k0 + kk];
        }
        __syncthreads();
#pragma unroll
        for (int kk = 0; kk < 16; ++kk) {
            float a[4], bb[4];
#pragma unroll
            for (int i = 0; i < 4; ++i) a[i] = As[kk][ty * 4 + i];
#pragma unroll
            for (int j = 0; j < 4; ++j) bb[j] = Bs[kk][tx * 4 + j];
#pragma unroll
            for (int i = 0; i < 4; ++i)
#pragma unroll
                for (int j = 0; j < 4; ++j)
                    acc[i][j] += a[i] * bb[j];
        }
    }

#pragma unroll
    for (int i = 0; i < 4; ++i) {
#pragma unroll
        for (int j = 0; j < 4; ++j) {
            int m = m0 + ty * 4 + i;
            int n = n0 + tx * 4 + j;
            if (headLayout) {
                int b = m >> 11;          // m / L
                int l = m & 2047;         // m % L
                int h = n >> 6;           // n / HD
                int c = n & 63;           // n % HD
                Y[(((size_t)(b * NHq + h)) * Lq + l) * HDq + c] = acc[i][j];
            } else {
                Y[(size_t)m * DIMq + n] = acc[i][j];
            }
        }
    }
}

// ---------------------------------------------------------------------------
// Flash-style attention forward, fp32.
// Q/K/V in [B][NH][L][HD].  One block per (q-tile of 64 rows, head, batch).
// Thread t: q-row r = t&63, key/col segment g = t>>6 (16 keys / 16 out cols).
// Online softmax; bias tile staged through LDS (coalesced); scores never hit
// HBM.  AO out: [B][L][DIM].
// ---------------------------------------------------------------------------
__global__ __launch_bounds__(256)
void attn_fwd(const float* __restrict__ Qh, const float* __restrict__ Kh,
              const float* __restrict__ Vh, const float* __restrict__ pos_bias,
              const int* __restrict__ mask, float* __restrict__ AO)
{
    const int qt = blockIdx.x;   // 0..31
    const int h  = blockIdx.y;   // 0..11
    const int b  = blockIdx.z;   // 0..1
    const float* Q = Qh + ((size_t)(b * NHq + h)) * Lq * HDq;
    const float* K = Kh + ((size_t)(b * NHq + h)) * Lq * HDq;
    const float* V = Vh + ((size_t)(b * NHq + h)) * Lq * HDq;
    const float* bias = pos_bias + ((size_t)h * Lq + (size_t)qt * 64) * Lq;
    const int* mk = mask + (size_t)b * Lq;

    __shared__ float KQ[64][65];   // Q tile, then K tiles
    __shared__ float Vs[64][65];
    __shared__ float PB[64][65];   // bias tile, then P tile
    __shared__ float redm[4][64];
    __shared__ float redl[4][64];
    __shared__ int   mks[64];

    const int tid = threadIdx.x;
    const int r = tid & 63;
    const int g = tid >> 6;

    // stage Q tile (coalesced), then pull this thread's q row into registers
#pragma unroll
    for (int i = 0; i < 16; ++i) {
        int idx = tid + i * 256, rr = idx >> 6, cc = idx & 63;
        KQ[rr][cc] = Q[(size_t)(qt * 64 + rr) * HDq + cc];
    }
    __syncthreads();
    float qreg[64];
#pragma unroll
    for (int c = 0; c < 64; ++c) qreg[c] = KQ[r][c];

    float o[16];
#pragma unroll
    for (int i = 0; i < 16; ++i) o[i] = 0.f;
    float m_run = -1e30f, l_run = 0.f;

    for (int kt = 0; kt < Lq / 64; ++kt) {
        __syncthreads();   // (a) previous tile fully consumed
#pragma unroll
        for (int i = 0; i < 16; ++i) {
            int idx = tid + i * 256, rr = idx >> 6, cc = idx & 63;
            KQ[rr][cc] = K[(size_t)(kt * 64 + rr) * HDq + cc];
            Vs[rr][cc] = V[(size_t)(kt * 64 + rr) * HDq + cc];
            PB[rr][cc] = bias[(size_t)rr * Lq + kt * 64 + cc];
        }
        if (tid < 64) mks[tid] = mk[kt * 64 + tid];
        __syncthreads();   // (b) tiles visible

        // scores for this thread's 16 keys
        float s[16];
#pragma unroll
        for (int jj = 0; jj < 16; ++jj) s[jj] = 0.f;
        for (int c = 0; c < 64; ++c) {
            float qv = qreg[c];
#pragma unroll
            for (int jj = 0; jj < 16; ++jj)
                s[jj] += qv * KQ[g * 16 + jj][c];
        }
        float tmax = -1e30f;
#pragma unroll
        for (int jj = 0; jj < 16; ++jj) {
            float sv = s[jj] + PB[r][g * 16 + jj];
            sv = (mks[g * 16 + jj] == 0) ? -1e30f : sv;
            s[jj] = sv;
            tmax = fmaxf(tmax, sv);
        }
        redm[g][r] = tmax;
        __syncthreads();   // (c) row maxima ready; all bias reads done

        float rowmax = fmaxf(fmaxf(redm[0][r], redm[1][r]),
                             fmaxf(redm[2][r], redm[3][r]));
        float mnew  = fmaxf(m_run, rowmax);
        float alpha = __expf(m_run - mnew);
        float psum = 0.f;
        float p[16];
#pragma unroll
        for (int jj = 0; jj < 16; ++jj) {
            float pv = __expf(s[jj] - mnew);
            pv = (mks[g * 16 + jj] == 0) ? 0.f : pv;
            p[jj] = pv;
            psum += pv;
        }
        redl[g][r] = psum;
#pragma unroll
        for (int jj = 0; jj < 16; ++jj) PB[r][g * 16 + jj] = p[jj];
        __syncthreads();   // (d) P tile + partial sums visible

        float lrow = redl[0][r] + redl[1][r] + redl[2][r] + redl[3][r];
        l_run = l_run * alpha + lrow;
        m_run = mnew;
#pragma unroll
        for (int i = 0; i < 16; ++i) o[i] *= alpha;
        for (int j = 0; j < 64; ++j) {
            float pv = PB[r][j];
#pragma unroll
            for (int cc = 0; cc < 16; ++cc)
                o[cc] += pv * Vs[j][g * 16 + cc];
        }
    }

    float inv = 1.0f / l_run;
    float* aoRow = AO + ((size_t)b * Lq + (size_t)qt * 64 + r) * DIMq
                 + h * HDq + g * 16;
#pragma unroll
    for (int cc = 0; cc < 16; ++cc) aoRow[cc] = o[cc] * inv;
}

// ---------------------------------------------------------------------------
extern "C" void kernel_launch(void* const* d_in, const int* in_sizes, int n_in,
                              void* d_out, int out_size, void* d_ws, size_t ws_size,
                              hipStream_t stream) {
    const float* x        = (const float*)d_in[0];
    const float* pos_bias = (const float*)d_in[1];
    const float* Wq       = (const float*)d_in[2];
    const float* Wk       = (const float*)d_in[3];
    const float* Wv       = (const float*)d_in[4];
    const float* Wo       = (const float*)d_in[5];
    const int*   mask     = (const int*)d_in[6];
    float* out = (float*)d_out;

    const size_t per = (size_t)Bq * NHq * Lq * HDq;   // 3,145,728 floats
    float* Qh = (float*)d_ws;
    float* Kh = Qh + per;
    float* Vh = Kh + per;
    float* AO = Vh + per;   // [B][L][DIM]

    dim3 blk(256);
    dim3 ggrid(DIMq / 64, (Bq * Lq) / 64);   // 12 x 64
    hipLaunchKernelGGL(gemm_xwt, ggrid, blk, 0, stream, x, Wq, Qh, 1);
    hipLaunchKernelGGL(gemm_xwt, ggrid, blk, 0, stream, x, Wk, Kh, 1);
    hipLaunchKernelGGL(gemm_xwt, ggrid, blk, 0, stream, x, Wv, Vh, 1);

    dim3 agrid(Lq / 64, NHq, Bq);            // 32 x 12 x 2
    hipLaunchKernelGGL(attn_fwd, agrid, blk, 0, stream,
                       Qh, Kh, Vh, pos_bias, mask, AO);

    hipLaunchKernelGGL(gemm_xwt, ggrid, blk, 0, stream, AO, Wo, out, 0);
}

// Round 2
// 809.965 us; speedup vs baseline: 3.6380x; 3.6380x over previous
//
#include <hip/hip_runtime.h>
#include <math.h>

#define Bq 2
#define Lq 2048
#define DIMq 768
#define NHq 12
#define HDq 64

typedef __attribute__((ext_vector_type(8))) short short8;
typedef __attribute__((ext_vector_type(4))) short short4v;
typedef __attribute__((ext_vector_type(4))) float float4v;

static __device__ __forceinline__ short f2bf(float f) {
    union { float f; unsigned u; } v; v.f = f;
    unsigned r = (v.u + 0x7FFF + ((v.u >> 16) & 1)) >> 16;   // RNE
    return (short)r;
}

// ---------------------------------------------------------------------------
// GEMM: Y = X @ W^T (fp32, unchanged from R1).
// ---------------------------------------------------------------------------
__global__ __launch_bounds__(256)
void gemm_xwt(const float* __restrict__ X, const float* __restrict__ W,
              float* __restrict__ Y, int headLayout)
{
    __shared__ float As[16][65];
    __shared__ float Bs[16][65];
    const int tid = threadIdx.x;
    const int tx = tid & 15, ty = tid >> 4;
    const int m0 = blockIdx.y * 64, n0 = blockIdx.x * 64;

    float acc[4][4];
#pragma unroll
    for (int i = 0; i < 4; ++i)
#pragma unroll
        for (int j = 0; j < 4; ++j) acc[i][j] = 0.f;

    for (int k0 = 0; k0 < DIMq; k0 += 16) {
        __syncthreads();
#pragma unroll
        for (int i = 0; i < 4; ++i) {
            int idx = tid + i * 256;
            int kk = idx & 15, mm = idx >> 4;
            As[kk][mm] = X[(size_t)(m0 + mm) * DIMq + k0 + kk];
            Bs[kk][mm] = W[(size_t)(n0 + mm) * DIMq + k0 + kk];
        }
        __syncthreads();
#pragma unroll
        for (int kk = 0; kk < 16; ++kk) {
            float a[4], bb[4];
#pragma unroll
            for (int i = 0; i < 4; ++i) a[i] = As[kk][ty * 4 + i];
#pragma unroll
            for (int j = 0; j < 4; ++j) bb[j] = Bs[kk][tx * 4 + j];
#pragma unroll
            for (int i = 0; i < 4; ++i)
#pragma unroll
                for (int j = 0; j < 4; ++j)
                    acc[i][j] += a[i] * bb[j];
        }
    }

#pragma unroll
    for (int i = 0; i < 4; ++i) {
#pragma unroll
        for (int j = 0; j < 4; ++j) {
            int m = m0 + ty * 4 + i;
            int n = n0 + tx * 4 + j;
            if (headLayout) {
                int b = m >> 11;
                int l = m & 2047;
                int h = n >> 6;
                int c = n & 63;
                Y[(((size_t)(b * NHq + h)) * Lq + l) * HDq + c] = acc[i][j];
            } else {
                Y[(size_t)m * DIMq + n] = acc[i][j];
            }
        }
    }
}

// ---------------------------------------------------------------------------
// MFMA flash attention, bf16 inputs / fp32 accumulate.
// Block = 256 thr = 4 waves; block tile = 64 q-rows; wave w owns q-rows
// [w*16, w*16+16).  K-tiles of 64 keys.  mfma_f32_16x16x32_bf16:
//   A frag: lane holds A[m=lane&15][k=quad*8+j]   (8 bf16)
//   B frag: lane holds B[k=quad*8+j][n=lane&15]   (8 bf16)
//   C/D:    lane holds D[row=quad*4+reg][col=lane&15] (4 f32)
// Ks[key][hd] is the natural B-layout for QK^T; Vt[hd][key] for PV.
// P does an intra-wave LDS round-trip for the C->A layout transform.
// Bias is read straight into C-layout registers (64B/quad segments).
// ---------------------------------------------------------------------------
__global__ __launch_bounds__(256, 2)
void attn_fwd_mfma(const float* __restrict__ Qh, const float* __restrict__ Kh,
                   const float* __restrict__ Vh, const float* __restrict__ pos_bias,
                   const int* __restrict__ mask, float* __restrict__ AO)
{
    const int qt = blockIdx.x;   // 0..31
    const int h  = blockIdx.y;   // 0..11
    const int b  = blockIdx.z;   // 0..1
    const float* Q = Qh + ((size_t)(b * NHq + h)) * Lq * HDq;
    const float* K = Kh + ((size_t)(b * NHq + h)) * Lq * HDq;
    const float* V = Vh + ((size_t)(b * NHq + h)) * Lq * HDq;
    const int* mk = mask + (size_t)b * Lq;

    __shared__ __align__(16) short Ks[64][72];  // [key][hd], +8 pad
    __shared__ __align__(16) short Vt[64][72];  // [hd][key], +8 pad
    __shared__ __align__(16) short Ps[64][72];  // [qrow][key], +8 pad
    __shared__ float smask[64];

    const int tid  = threadIdx.x;
    const int wave = tid >> 6;
    const int lane = tid & 63;
    const int col  = lane & 15;
    const int quad = lane >> 4;

    // --- persistent Q A-frags (rows qt*64 + wave*16 + col) ---
    short8 qa[2];
    {
        const float* qrow = Q + (size_t)(qt * 64 + wave * 16 + col) * HDq;
#pragma unroll
        for (int kk = 0; kk < 2; ++kk) {
            short8 f;
#pragma unroll
            for (int j = 0; j < 8; ++j)
                f[j] = f2bf(qrow[kk * 32 + quad * 8 + j]);
            qa[kk] = f;
        }
    }

    // bias pointer for this lane's C-layout rows (element (nt,reg) at
    // brow[reg*L + kt*64 + 16*nt])
    const float* brow = pos_bias + (size_t)h * Lq * Lq
                      + (size_t)(qt * 64 + wave * 16 + quad * 4) * Lq + col;

    float4v Oacc[4];
    float m_run[4], l_run[4];
#pragma unroll
    for (int nt = 0; nt < 4; ++nt) Oacc[nt] = (float4v){0.f, 0.f, 0.f, 0.f};
#pragma unroll
    for (int r = 0; r < 4; ++r) { m_run[r] = -1e30f; l_run[r] = 0.f; }

    for (int kt = 0; kt < Lq / 64; ++kt) {
        __syncthreads();   // prior iteration's LDS reads done
        // --- stage K tile: [key][hd], coalesced float4 reads ---
        const float4* K4 = (const float4*)(K + (size_t)kt * 64 * HDq);
        const float4* V4 = (const float4*)(V + (size_t)kt * 64 * HDq);
#pragma unroll
        for (int i = 0; i < 4; ++i) {
            int idx = tid + i * 256;
            int key = idx >> 4, hq = idx & 15;
            float4 kv = K4[key * 16 + hq];
            short4v ks4;
            ks4[0] = f2bf(kv.x); ks4[1] = f2bf(kv.y);
            ks4[2] = f2bf(kv.z); ks4[3] = f2bf(kv.w);
            *(short4v*)&Ks[key][hq * 4] = ks4;
        }
        // --- stage V tile transposed: [hd][key] ---
#pragma unroll
        for (int i = 0; i < 4; ++i) {
            int key = tid & 63;
            int hg  = (tid >> 6) + i * 4;
            float4 vv = V4[key * 16 + hg];
            Vt[hg * 4 + 0][key] = f2bf(vv.x);
            Vt[hg * 4 + 1][key] = f2bf(vv.y);
            Vt[hg * 4 + 2][key] = f2bf(vv.z);
            Vt[hg * 4 + 3][key] = f2bf(vv.w);
        }
        if (tid < 64) smask[tid] = (mk[kt * 64 + tid] == 0) ? -1e30f : 0.0f;
        __syncthreads();   // tiles visible

        // --- QK^T : S[16 x 64] per wave ---
        float4v S[4];
#pragma unroll
        for (int nt = 0; nt < 4; ++nt) S[nt] = (float4v){0.f, 0.f, 0.f, 0.f};
#pragma unroll
        for (int kk = 0; kk < 2; ++kk) {
#pragma unroll
            for (int nt = 0; nt < 4; ++nt) {
                short8 bfr = *(const short8*)&Ks[nt * 16 + col][kk * 32 + quad * 8];
                S[nt] = __builtin_amdgcn_mfma_f32_16x16x32_bf16(qa[kk], bfr, S[nt], 0, 0, 0);
            }
        }

        // --- bias + mask, online softmax ---
        float sc[4][4];
#pragma unroll
        for (int nt = 0; nt < 4; ++nt) {
            float mnt = smask[col + 16 * nt];
#pragma unroll
            for (int reg = 0; reg < 4; ++reg)
                sc[nt][reg] = S[nt][reg] + brow[(size_t)reg * Lq + kt * 64 + 16 * nt] + mnt;
        }
        float tm[4];
#pragma unroll
        for (int reg = 0; reg < 4; ++reg) {
            tm[reg] = fmaxf(fmaxf(sc[0][reg], sc[1][reg]),
                            fmaxf(sc[2][reg], sc[3][reg]));
#pragma unroll
            for (int off = 1; off < 16; off <<= 1)
                tm[reg] = fmaxf(tm[reg], __shfl_xor(tm[reg], off, 64));
        }
        float alpha[4], ps[4];
#pragma unroll
        for (int reg = 0; reg < 4; ++reg) {
            float mn = fmaxf(m_run[reg], tm[reg]);
            alpha[reg] = __expf(m_run[reg] - mn);
            m_run[reg] = mn;
            ps[reg] = 0.f;
        }
#pragma unroll
        for (int nt = 0; nt < 4; ++nt)
#pragma unroll
            for (int reg = 0; reg < 4; ++reg) {
                float p = __expf(sc[nt][reg] - m_run[reg]);
                sc[nt][reg] = p;
                ps[reg] += p;
            }
#pragma unroll
        for (int reg = 0; reg < 4; ++reg) {
#pragma unroll
            for (int off = 1; off < 16; off <<= 1)
                ps[reg] += __shfl_xor(ps[reg], off, 64);
            l_run[reg] = l_run[reg] * alpha[reg] + ps[reg];
        }
        // --- P -> LDS (C-layout write; A-layout read is intra-wave) ---
#pragma unroll
        for (int nt = 0; nt < 4; ++nt)
#pragma unroll
            for (int reg = 0; reg < 4; ++reg)
                Ps[wave * 16 + quad * 4 + reg][col + 16 * nt] = f2bf(sc[nt][reg]);
        // --- rescale O ---
#pragma unroll
        for (int nt = 0; nt < 4; ++nt)
#pragma unroll
            for (int reg = 0; reg < 4; ++reg)
                Oacc[nt][reg] *= alpha[reg];
        __syncthreads();   // P visible (also orders vs next staging)

        // --- PV : O += P[16x64] @ V[64x64] ---
#pragma unroll
        for (int kk = 0; kk < 2; ++kk) {
            short8 pa = *(const short8*)&Ps[wave * 16 + col][kk * 32 + quad * 8];
#pragma unroll
            for (int nt = 0; nt < 4; ++nt) {
                short8 vb = *(const short8*)&Vt[nt * 16 + col][kk * 32 + quad * 8];
                Oacc[nt] = __builtin_amdgcn_mfma_f32_16x16x32_bf16(pa, vb, Oacc[nt], 0, 0, 0);
            }
        }
    }

    // --- epilogue: AO[b][l][h*64 + c] ---
    float* aorow = AO + ((size_t)b * Lq + qt * 64 + wave * 16 + quad * 4) * DIMq
                 + h * HDq + col;
#pragma unroll
    for (int reg = 0; reg < 4; ++reg) {
        float inv = 1.0f / l_run[reg];
#pragma unroll
        for (int nt = 0; nt < 4; ++nt)
            aorow[(size_t)reg * DIMq + 16 * nt] = Oacc[nt][reg] * inv;
    }
}

// ---------------------------------------------------------------------------
extern "C" void kernel_launch(void* const* d_in, const int* in_sizes, int n_in,
                              void* d_out, int out_size, void* d_ws, size_t ws_size,
                              hipStream_t stream) {
    const float* x        = (const float*)d_in[0];
    const float* pos_bias = (const float*)d_in[1];
    const float* Wq       = (const float*)d_in[2];
    const float* Wk       = (const float*)d_in[3];
    const float* Wv       = (const float*)d_in[4];
    const float* Wo       = (const float*)d_in[5];
    const int*   mask     = (const int*)d_in[6];
    float* out = (float*)d_out;

    const size_t per = (size_t)Bq * NHq * Lq * HDq;
    float* Qh = (float*)d_ws;
    float* Kh = Qh + per;
    float* Vh = Kh + per;
    float* AO = Vh + per;   // [B][L][DIM]

    dim3 blk(256);
    dim3 ggrid(DIMq / 64, (Bq * Lq) / 64);
    hipLaunchKernelGGL(gemm_xwt, ggrid, blk, 0, stream, x, Wq, Qh, 1);
    hipLaunchKernelGGL(gemm_xwt, ggrid, blk, 0, stream, x, Wk, Kh, 1);
    hipLaunchKernelGGL(gemm_xwt, ggrid, blk, 0, stream, x, Wv, Vh, 1);

    dim3 agrid(Lq / 64, NHq, Bq);
    hipLaunchKernelGGL(attn_fwd_mfma, agrid, blk, 0, stream,
                       Qh, Kh, Vh, pos_bias, mask, AO);

    hipLaunchKernelGGL(gemm_xwt, ggrid, blk, 0, stream, AO, Wo, out, 0);
}

// Round 3
// 425.998 us; speedup vs baseline: 6.9170x; 1.9013x over previous
//
#include <hip/hip_runtime.h>
#include <math.h>

#define Bq 2
#define Lq 2048
#define DIMq 768
#define NHq 12
#define HDq 64

typedef __attribute__((ext_vector_type(8))) short short8;
typedef __attribute__((ext_vector_type(4))) short short4v;
typedef __attribute__((ext_vector_type(4))) float float4v;

static __device__ __forceinline__ short f2bf(float f) {
    union { float f; unsigned u; } v; v.f = f;
    unsigned r = (v.u + 0x7FFF + ((v.u >> 16) & 1)) >> 16;   // RNE
    return (short)r;
}

// ---------------------------------------------------------------------------
// fp32 -> bf16 conversion for x and the four weight matrices.
// Region table: x = 768 blocks of 1024 float4; each W = 144 blocks.
// ---------------------------------------------------------------------------
__global__ __launch_bounds__(256)
void to_bf16(const float* __restrict__ x,  const float* __restrict__ wq,
             const float* __restrict__ wk, const float* __restrict__ wv,
             const float* __restrict__ wo,
             short* __restrict__ xb, short* __restrict__ wqb,
             short* __restrict__ wkb, short* __restrict__ wvb,
             short* __restrict__ wob)
{
    int blk = blockIdx.x;
    const float* s; short* d; int off;
    if      (blk <  768) { s = x;  d = xb;  off = blk * 1024; }
    else if (blk <  912) { s = wq; d = wqb; off = (blk -  768) * 1024; }
    else if (blk < 1056) { s = wk; d = wkb; off = (blk -  912) * 1024; }
    else if (blk < 1200) { s = wv; d = wvb; off = (blk - 1056) * 1024; }
    else                 { s = wo; d = wob; off = (blk - 1200) * 1024; }
    const float4* s4 = (const float4*)s;
    short4v* d4 = (short4v*)d;
#pragma unroll
    for (int i = 0; i < 4; ++i) {
        int idx = off + threadIdx.x + i * 256;
        float4 v = s4[idx];
        short4v o;
        o[0] = f2bf(v.x); o[1] = f2bf(v.y); o[2] = f2bf(v.z); o[3] = f2bf(v.w);
        d4[idx] = o;
    }
}

// ---------------------------------------------------------------------------
// bf16 MFMA GEMM: C = A @ W^T.  A: [M,768] bf16, W: [768,768] bf16 (row-major,
// torch Linear weight).  64x64 tile, BK=64, 256 thr = 4 waves; wave w computes
// rows [w*16, w*16+16) x all 64 cols via 16x16x32 MFMA.
// mode 1: write bf16 split-head [B][NH][L][HD] (dst selected by blockIdx.z).
// mode 0: write fp32 flat [M][768] to DF.
// ---------------------------------------------------------------------------
__global__ __launch_bounds__(256, 2)
void gemm_bf16(const short* __restrict__ A,
               const short* __restrict__ W0, const short* __restrict__ W1,
               const short* __restrict__ W2,
               short* __restrict__ D0, short* __restrict__ D1,
               short* __restrict__ D2, float* __restrict__ DF, int mode)
{
    const int z = blockIdx.z;
    const short* W = (z == 0) ? W0 : ((z == 1) ? W1 : W2);
    short* DH = (z == 0) ? D0 : ((z == 1) ? D1 : D2);

    __shared__ __align__(16) short Xs[64][72];
    __shared__ __align__(16) short Ws[64][72];

    const int tid  = threadIdx.x;
    const int wave = tid >> 6;
    const int lane = tid & 63;
    const int col  = lane & 15;
    const int quad = lane >> 4;
    const int m0 = blockIdx.y * 64, n0 = blockIdx.x * 64;

    float4v acc[4];
#pragma unroll
    for (int nt = 0; nt < 4; ++nt) acc[nt] = (float4v){0.f, 0.f, 0.f, 0.f};

    for (int k0 = 0; k0 < DIMq; k0 += 64) {
        __syncthreads();
#pragma unroll
        for (int i = 0; i < 2; ++i) {
            int idx = tid + i * 256;          // 512 chunks of 8 shorts
            int mm = idx >> 3, ch = idx & 7;
            *(short8*)&Xs[mm][ch * 8] =
                *(const short8*)&A[(size_t)(m0 + mm) * DIMq + k0 + ch * 8];
            *(short8*)&Ws[mm][ch * 8] =
                *(const short8*)&W[(size_t)(n0 + mm) * DIMq + k0 + ch * 8];
        }
        __syncthreads();
#pragma unroll
        for (int kk = 0; kk < 2; ++kk) {
            short8 a = *(const short8*)&Xs[wave * 16 + col][kk * 32 + quad * 8];
#pragma unroll
            for (int nt = 0; nt < 4; ++nt) {
                short8 bfr = *(const short8*)&Ws[nt * 16 + col][kk * 32 + quad * 8];
                acc[nt] = __builtin_amdgcn_mfma_f32_16x16x32_bf16(a, bfr, acc[nt], 0, 0, 0);
            }
        }
    }

#pragma unroll
    for (int reg = 0; reg < 4; ++reg) {
        int m = m0 + wave * 16 + quad * 4 + reg;
#pragma unroll
        for (int nt = 0; nt < 4; ++nt) {
            int n = n0 + 16 * nt + col;
            if (mode == 1) {
                int b = m >> 11, l = m & 2047, h = n >> 6, c = n & 63;
                DH[(((size_t)(b * NHq + h)) * Lq + l) * HDq + c] = f2bf(acc[nt][reg]);
            } else {
                DF[(size_t)m * DIMq + n] = acc[nt][reg];
            }
        }
    }
}

// ---------------------------------------------------------------------------
// MFMA flash attention, bf16 Q/K/V in [B][NH][L][HD]; bias+mask prefetched
// into registers one K-tile ahead; AO written as bf16 [B][L][DIM].
// ---------------------------------------------------------------------------
__global__ __launch_bounds__(256, 2)
void attn_fwd_mfma(const short* __restrict__ Qh, const short* __restrict__ Kh,
                   const short* __restrict__ Vh, const float* __restrict__ pos_bias,
                   const int* __restrict__ mask, short* __restrict__ AO)
{
    const int qt = blockIdx.x;   // 0..31
    const int h  = blockIdx.y;   // 0..11
    const int b  = blockIdx.z;   // 0..1
    const short* Q = Qh + ((size_t)(b * NHq + h)) * Lq * HDq;
    const short* K = Kh + ((size_t)(b * NHq + h)) * Lq * HDq;
    const short* V = Vh + ((size_t)(b * NHq + h)) * Lq * HDq;
    const int* mk = mask + (size_t)b * Lq;

    __shared__ __align__(16) short Ks[64][72];  // [key][hd]
    __shared__ __align__(16) short Vt[64][72];  // [hd][key]
    __shared__ __align__(16) short Ps[64][72];  // [qrow][key]

    const int tid  = threadIdx.x;
    const int wave = tid >> 6;
    const int lane = tid & 63;
    const int col  = lane & 15;
    const int quad = lane >> 4;

    // persistent Q A-frags
    short8 qa[2];
    {
        const short* qrow = Q + (size_t)(qt * 64 + wave * 16 + col) * HDq;
        qa[0] = *(const short8*)&qrow[quad * 8];
        qa[1] = *(const short8*)&qrow[32 + quad * 8];
    }

    // bias element (nt,reg) at brow[reg*L + kt*64 + 16*nt]
    const float* brow = pos_bias + (size_t)h * Lq * Lq
                      + (size_t)(qt * 64 + wave * 16 + quad * 4) * Lq + col;

    float bcur[4][4], bnxt[4][4];
    auto prefetch = [&](int kt, float (&bb)[4][4]) {
#pragma unroll
        for (int nt = 0; nt < 4; ++nt) {
            int mval = mk[kt * 64 + col + 16 * nt];
            float fm = (mval == 0) ? -1e30f : 0.0f;
#pragma unroll
            for (int reg = 0; reg < 4; ++reg)
                bb[nt][reg] = brow[(size_t)reg * Lq + kt * 64 + 16 * nt] + fm;
        }
    };
    prefetch(0, bcur);

    float4v Oacc[4];
    float m_run[4], l_run[4];
#pragma unroll
    for (int nt = 0; nt < 4; ++nt) Oacc[nt] = (float4v){0.f, 0.f, 0.f, 0.f};
#pragma unroll
    for (int r = 0; r < 4; ++r) { m_run[r] = -1e30f; l_run[r] = 0.f; }

    for (int kt = 0; kt < Lq / 64; ++kt) {
        __syncthreads();   // prior iteration's LDS reads complete
        // --- stage K tile [key][hd]: 512 chunks of 8 shorts ---
        const short* Kt = K + (size_t)kt * 64 * HDq;
        const short* Vg = V + (size_t)kt * 64 * HDq;
#pragma unroll
        for (int i = 0; i < 2; ++i) {
            int idx = tid + i * 256;
            int key = idx >> 3, ch = idx & 7;
            *(short8*)&Ks[key][ch * 8] = *(const short8*)&Kt[key * HDq + ch * 8];
        }
        // --- stage V transposed [hd][key] ---
        {
            int key = tid & 63, hg = tid >> 6;
#pragma unroll
            for (int i = 0; i < 2; ++i) {
                int c = hg + i * 4;          // hd chunk 0..7
                short8 vv = *(const short8*)&Vg[key * HDq + c * 8];
#pragma unroll
                for (int j = 0; j < 8; ++j)
                    Vt[c * 8 + j][key] = vv[j];
            }
        }
        // --- prefetch next tile's bias+mask into registers ---
        if (kt + 1 < Lq / 64) prefetch(kt + 1, bnxt);
        __syncthreads();   // tiles visible

        // --- QK^T ---
        float4v S[4];
#pragma unroll
        for (int nt = 0; nt < 4; ++nt) S[nt] = (float4v){0.f, 0.f, 0.f, 0.f};
#pragma unroll
        for (int kk = 0; kk < 2; ++kk) {
#pragma unroll
            for (int nt = 0; nt < 4; ++nt) {
                short8 bfr = *(const short8*)&Ks[nt * 16 + col][kk * 32 + quad * 8];
                S[nt] = __builtin_amdgcn_mfma_f32_16x16x32_bf16(qa[kk], bfr, S[nt], 0, 0, 0);
            }
        }

        // --- bias + mask + online softmax ---
        float sc[4][4];
#pragma unroll
        for (int nt = 0; nt < 4; ++nt)
#pragma unroll
            for (int reg = 0; reg < 4; ++reg)
                sc[nt][reg] = S[nt][reg] + bcur[nt][reg];
        float tm[4];
#pragma unroll
        for (int reg = 0; reg < 4; ++reg) {
            tm[reg] = fmaxf(fmaxf(sc[0][reg], sc[1][reg]),
                            fmaxf(sc[2][reg], sc[3][reg]));
#pragma unroll
            for (int off = 1; off < 16; off <<= 1)
                tm[reg] = fmaxf(tm[reg], __shfl_xor(tm[reg], off, 64));
        }
        float alpha[4], ps[4];
#pragma unroll
        for (int reg = 0; reg < 4; ++reg) {
            float mn = fmaxf(m_run[reg], tm[reg]);
            alpha[reg] = __expf(m_run[reg] - mn);
            m_run[reg] = mn;
            ps[reg] = 0.f;
        }
#pragma unroll
        for (int nt = 0; nt < 4; ++nt)
#pragma unroll
            for (int reg = 0; reg < 4; ++reg) {
                float p = __expf(sc[nt][reg] - m_run[reg]);
                sc[nt][reg] = p;
                ps[reg] += p;
            }
#pragma unroll
        for (int reg = 0; reg < 4; ++reg) {
#pragma unroll
            for (int off = 1; off < 16; off <<= 1)
                ps[reg] += __shfl_xor(ps[reg], off, 64);
            l_run[reg] = l_run[reg] * alpha[reg] + ps[reg];
        }
        // --- P -> LDS (C-layout write, A-layout read is intra-wave) ---
#pragma unroll
        for (int nt = 0; nt < 4; ++nt)
#pragma unroll
            for (int reg = 0; reg < 4; ++reg)
                Ps[wave * 16 + quad * 4 + reg][col + 16 * nt] = f2bf(sc[nt][reg]);
#pragma unroll
        for (int nt = 0; nt < 4; ++nt)
#pragma unroll
            for (int reg = 0; reg < 4; ++reg)
                Oacc[nt][reg] *= alpha[reg];
        __syncthreads();   // P visible

        // --- PV ---
#pragma unroll
        for (int kk = 0; kk < 2; ++kk) {
            short8 pa = *(const short8*)&Ps[wave * 16 + col][kk * 32 + quad * 8];
#pragma unroll
            for (int nt = 0; nt < 4; ++nt) {
                short8 vb = *(const short8*)&Vt[nt * 16 + col][kk * 32 + quad * 8];
                Oacc[nt] = __builtin_amdgcn_mfma_f32_16x16x32_bf16(pa, vb, Oacc[nt], 0, 0, 0);
            }
        }
        // rotate bias double-buffer
#pragma unroll
        for (int nt = 0; nt < 4; ++nt)
#pragma unroll
            for (int reg = 0; reg < 4; ++reg)
                bcur[nt][reg] = bnxt[nt][reg];
    }

    // --- epilogue: AO bf16 [B][L][DIM] ---
    short* aorow = AO + ((size_t)b * Lq + qt * 64 + wave * 16 + quad * 4) * DIMq
                 + h * HDq + col;
#pragma unroll
    for (int reg = 0; reg < 4; ++reg) {
        float inv = 1.0f / l_run[reg];
#pragma unroll
        for (int nt = 0; nt < 4; ++nt)
            aorow[(size_t)reg * DIMq + 16 * nt] = f2bf(Oacc[nt][reg] * inv);
    }
}

// ---------------------------------------------------------------------------
extern "C" void kernel_launch(void* const* d_in, const int* in_sizes, int n_in,
                              void* d_out, int out_size, void* d_ws, size_t ws_size,
                              hipStream_t stream) {
    const float* x        = (const float*)d_in[0];
    const float* pos_bias = (const float*)d_in[1];
    const float* Wq       = (const float*)d_in[2];
    const float* Wk       = (const float*)d_in[3];
    const float* Wv       = (const float*)d_in[4];
    const float* Wo       = (const float*)d_in[5];
    const int*   mask     = (const int*)d_in[6];
    float* out = (float*)d_out;

    const size_t nX = (size_t)Bq * Lq * DIMq;       // 3,145,728
    const size_t nW = (size_t)DIMq * DIMq;          //   589,824
    short* xb  = (short*)d_ws;
    short* wqb = xb  + nX;
    short* wkb = wqb + nW;
    short* wvb = wkb + nW;
    short* wob = wvb + nW;
    short* Qh  = wob + nW;
    short* Kh  = Qh  + nX;
    short* Vh  = Kh  + nX;
    short* AOb = Vh  + nX;

    dim3 blk(256);
    hipLaunchKernelGGL(to_bf16, dim3(1344), blk, 0, stream,
                       x, Wq, Wk, Wv, Wo, xb, wqb, wkb, wvb, wob);

    // fused QKV projections (z selects weight/dst), bf16 head-layout out
    hipLaunchKernelGGL(gemm_bf16, dim3(DIMq / 64, (Bq * Lq) / 64, 3), blk, 0, stream,
                       xb, wqb, wkb, wvb, Qh, Kh, Vh, (float*)nullptr, 1);

    hipLaunchKernelGGL(attn_fwd_mfma, dim3(Lq / 64, NHq, Bq), blk, 0, stream,
                       Qh, Kh, Vh, pos_bias, mask, AOb);

    // output projection, fp32 out
    hipLaunchKernelGGL(gemm_bf16, dim3(DIMq / 64, (Bq * Lq) / 64, 1), blk, 0, stream,
                       AOb, wob, wob, wob, (short*)nullptr, (short*)nullptr,
                       (short*)nullptr, out, 0);
}